// Round 5
// baseline (807.558 us; speedup 1.0000x reference)
//
#include <hip/hip_runtime.h>
#include <stdint.h>
#include <stddef.h>

typedef __bf16 bf16;
typedef bf16 bf16x4 __attribute__((ext_vector_type(4)));
typedef bf16 bf16x8 __attribute__((ext_vector_type(8)));
typedef float f32x4 __attribute__((ext_vector_type(4)));
typedef float f32x16 __attribute__((ext_vector_type(16)));

#define T_DIM 365
#define SX    376      // LDS stride (bf16) for Xb
#define SH1   520
#define SH2   264
#define SCB   184      // combined: 128 seq + 32 stat
#define SC1   72
#define SC2   33

#define ROWS  64

// Union region: fp32 x staging (Phase A) aliased over sH1 / sCB / sC2.
#define SU_H1    0
#define SU_CB    66560
#define SU_C2    90112
#define SU_BYTES 98816

// ws element offsets (bf16 elements) — fragment-major packed layouts (UNCHANGED).
#define WT1_OFF  0
#define WT2_OFF  188416
#define WT3_OFF  319488
#define WTC1_OFF 352256
#define WTC2_OFF 362496
#define WTOTAL   364544

// sConst float offsets
#define OB1   0
#define OB2   512
#define OB3   768
#define OBC1  896
#define OBC2  960
#define OWS   992
#define OBS   1184
#define OWC3  1216
#define OBC3  1248
#define NCONST 1252

__global__ void prep_weights(const float* __restrict__ W1, const float* __restrict__ W2,
                             const float* __restrict__ W3, const float* __restrict__ Wc1,
                             const float* __restrict__ Wc2, bf16* __restrict__ ws) {
    int idx = blockIdx.x * 256 + threadIdx.x;
    if (idx >= WTOTAL) return;
    if (idx < WT2_OFF) {
        int t = idx;
        int j = t & 7, lane = (t >> 3) & 63, f = t >> 9;
        int ks = f % 23; f /= 23;
        int nt = f & 3, wv = f >> 2;
        int n = 128 * wv + 32 * nt + (lane & 31);
        int k = 16 * ks + (lane >> 5) * 8 + j;
        ws[idx] = (k < T_DIM) ? (bf16)W1[k * 512 + n] : (bf16)0.0f;
    } else if (idx < WT3_OFF) {
        int t = idx - WT2_OFF;
        int j = t & 7, lane = (t >> 3) & 63, f = t >> 9;
        int ks = f & 31; f >>= 5;
        int nt = f & 1, wv = f >> 1;
        int n = 64 * wv + 32 * nt + (lane & 31);
        int k = 16 * ks + (lane >> 5) * 8 + j;
        ws[idx] = (bf16)W2[k * 256 + n];
    } else if (idx < WTC1_OFF) {
        int t = idx - WT3_OFF;
        int j = t & 7, lane = (t >> 3) & 63, f = t >> 9;
        int ks = f & 15, wv = f >> 4;
        int n = 32 * wv + (lane & 31);
        int k = 16 * ks + (lane >> 5) * 8 + j;
        ws[idx] = (bf16)W3[k * 128 + n];
    } else if (idx < WTC2_OFF) {
        int t = idx - WTC1_OFF;
        int j = t & 7, lane = (t >> 3) & 63, f = t >> 9;
        int ks = f % 5; f /= 5;
        int nt = f & 1, g = f >> 1;
        int n = 16 * (2 * g + nt) + (lane & 15);
        int k = 32 * ks + (lane >> 4) * 8 + j;
        ws[idx] = (bf16)Wc1[k * 64 + n];
    } else {
        int t = idx - WTC2_OFF;
        int j = t & 7, lane = (t >> 3) & 63, f = t >> 9;
        int ks = f & 1, nt = f >> 1;
        int n = 16 * nt + (lane & 15);
        int k = 32 * ks + (lane >> 4) * 8 + j;
        ws[idx] = (bf16)Wc2[k * 32 + n];
    }
}

__device__ inline f32x16 z16() {
    f32x16 v;
#pragma unroll
    for (int i = 0; i < 16; ++i) v[i] = 0.0f;
    return v;
}
__device__ inline f32x4 z4() {
    f32x4 v;
#pragma unroll
    for (int i = 0; i < 4; ++i) v[i] = 0.0f;
    return v;
}

__device__ __forceinline__ void bar_lgkm() {
    asm volatile("s_waitcnt lgkmcnt(0)" ::: "memory");
    __builtin_amdgcn_s_barrier();
}
__device__ __forceinline__ void bar_all() {
    asm volatile("s_waitcnt vmcnt(0) lgkmcnt(0)" ::: "memory");
    __builtin_amdgcn_s_barrier();
}

__device__ __forceinline__ void stage16(const float* g, void* ldsbase) {
    __builtin_amdgcn_global_load_lds(
        (const __attribute__((address_space(1))) void*)g,
        (__attribute__((address_space(3))) void*)ldsbase, 16, 0, 0);
}

// =====================================================================
// ABLATION A: Phase A only (staging + consts + stats + statfeat), x16 reps.
// Faithful copy of fused_mlp's Phase A. dur = 64 * T_A (grid 1024, 4/CU).
// Digest -> wt[blockIdx] (overwritten by prep_weights afterwards).
// =====================================================================
__global__ __launch_bounds__(512, 2) void abl_phaseA(
    const float* __restrict__ x, bf16* __restrict__ wtdig,
    const float* __restrict__ b1, const float* __restrict__ b2, const float* __restrict__ b3,
    const float* __restrict__ Ws, const float* __restrict__ bs,
    const float* __restrict__ bc1, const float* __restrict__ bc2,
    const float* __restrict__ Wc3, const float* __restrict__ bc3)
{
    __shared__ __align__(16) char  sU[SU_BYTES];
    __shared__ __align__(16) bf16  sXb[ROWS * SX];
    __shared__ __align__(16) float sConst[NCONST];
    bf16*  sCB = (bf16*)(sU + SU_CB);
    float* stg = (float*)sU;

    const int tid = threadIdx.x;
    const int wv  = tid >> 6;
    const int lane = tid & 63;
    float dg = 0.0f;

    for (int rep = 0; rep < 16; ++rep) {
        const int row0 = (int)(((unsigned)blockIdx.x + 127u * rep) & 1023u) * 64;
        const float* xt = x + (size_t)row0 * T_DIM;
#pragma unroll
        for (int i = 0; i < 12; ++i) {
            int s = i * 8 + wv;
            if (s < 91) {
                stage16(xt + s * 256 + lane * 4, (void*)(sU + (size_t)s * 1024));
            } else if (s == 91) {
                if (lane < 16)
                    stage16(xt + s * 256 + lane * 4, (void*)(sU + (size_t)s * 1024));
            }
        }
        sConst[OB1 + tid] = b1[tid];
        if (tid < 256)      sConst[OB2 + tid]        = b2[tid];
        else if (tid < 384) sConst[OB3 + tid - 256]  = b3[tid - 256];
        else if (tid < 448) sConst[OBC1 + tid - 384] = bc1[tid - 384];
        else if (tid < 480) sConst[OBC2 + tid - 448] = bc2[tid - 448];
        else                sConst[OWS + tid - 480]  = Ws[tid - 480];
        if (tid < 160)      sConst[OWS + 32 + tid]   = Ws[32 + tid];
        else if (tid < 192) sConst[OBS + tid - 160]  = bs[tid - 160];
        else if (tid < 224) sConst[OWC3 + tid - 192] = Wc3[tid - 192];
        else if (tid == 224) sConst[OBC3]            = bc3[0];

        bar_all();

        {
            const int r   = tid >> 3;
            const int j   = tid & 7;
            const int c0  = 46 * j;
            const int cnt = (j < 7) ? 46 : 43;
            const float* srow = stg + r * 365 + c0;
            bf16* xb = sXb + r * SX + c0;
            float s1 = 0.f, s2 = 0.f, s3 = 0.f, s4 = 0.f;
            float mn = 3.4e38f, mx = -3.4e38f;
#pragma unroll
            for (int i = 0; i < 46; ++i) {
                float v  = srow[i];
                bool ok  = (i < cnt);
                float vv = ok ? v : 0.0f;
                s1 += vv;
                float q = vv * vv;
                s2 += q; s3 += q * vv; s4 += q * q;
                mn = fminf(mn, ok ? v : 3.4e38f);
                mx = fmaxf(mx, ok ? v : -3.4e38f);
                xb[i] = (bf16)vv;
            }
#pragma unroll
            for (int m = 1; m < 8; m <<= 1) {
                s1 += __shfl_xor(s1, m); s2 += __shfl_xor(s2, m);
                s3 += __shfl_xor(s3, m); s4 += __shfl_xor(s4, m);
                mn = fminf(mn, __shfl_xor(mn, m));
                mx = fmaxf(mx, __shfl_xor(mx, m));
            }
            const float Tf = (float)T_DIM;
            float mu = s1 / Tf;
            float M2 = fmaxf(s2 - s1 * mu, 0.0f);
            float M3 = s3 - 3.f * mu * s2 + 2.f * Tf * mu * mu * mu;
            float M4 = s4 - 4.f * mu * s3 + 6.f * mu * mu * s2 - 3.f * Tf * mu * mu * mu * mu;
            float var = M2 / (Tf - 1.f);
            float sd  = sqrtf(var);
            float sk  = (M3 / Tf) / (sd * sd * sd + 1e-8f);
            float ku  = (M4 / Tf) / (var * var + 1e-8f);

            bar_lgkm();

#pragma unroll
            for (int cc = 0; cc < 4; ++cc) {
                int n = 4 * j + cc;
                float v = sConst[OBS + n]
                        + mu * sConst[OWS + 0*32+n] + sd * sConst[OWS + 1*32+n]
                        + mn * sConst[OWS + 2*32+n] + mx * sConst[OWS + 3*32+n]
                        + sk * sConst[OWS + 4*32+n] + ku * sConst[OWS + 5*32+n];
                sCB[r * SCB + 128 + n] = (bf16)v;
            }
            dg += mu + sd + mn + mx + sk + ku;
        }
        bar_lgkm();   // all reads of stg done before next rep's staging overwrites
    }
    if (tid == 0) wtdig[blockIdx.x] = (bf16)dg;
}

// =====================================================================
// ABLATION B: Phase A x1 + L1 phase x20 (faithful copy incl. prefetch
// prologue, 23-iter MFMA loop, epilogue, barrier). dur = 4*T_A + 80*T_L1.
// Digest -> wt[4096 + blockIdx].
// =====================================================================
__global__ __launch_bounds__(512, 2) void abl_L1(
    const float* __restrict__ x, const bf16* __restrict__ wt,
    const float* __restrict__ b1, const float* __restrict__ b2, const float* __restrict__ b3,
    const float* __restrict__ Ws, const float* __restrict__ bs,
    const float* __restrict__ bc1, const float* __restrict__ bc2,
    const float* __restrict__ Wc3, const float* __restrict__ bc3,
    bf16* __restrict__ wtdig)
{
    __shared__ __align__(16) char  sU[SU_BYTES];
    __shared__ __align__(16) bf16  sXb[ROWS * SX];
    __shared__ __align__(16) float sConst[NCONST];
    bf16*  sH1 = (bf16*)(sU + SU_H1);
    bf16*  sCB = (bf16*)(sU + SU_CB);
    float* stg = (float*)sU;

    const int tid  = threadIdx.x;
    const int lane = tid & 63;
    const int wv   = tid >> 6;
    const int row0 = blockIdx.x * ROWS;
    float dg = 0.0f;

    // ---- Phase A (verbatim) ----
    const float* xt = x + (size_t)row0 * T_DIM;
#pragma unroll
    for (int i = 0; i < 12; ++i) {
        int s = i * 8 + wv;
        if (s < 91) {
            stage16(xt + s * 256 + lane * 4, (void*)(sU + (size_t)s * 1024));
        } else if (s == 91) {
            if (lane < 16)
                stage16(xt + s * 256 + lane * 4, (void*)(sU + (size_t)s * 1024));
        }
    }
    sConst[OB1 + tid] = b1[tid];
    if (tid < 256)      sConst[OB2 + tid]        = b2[tid];
    else if (tid < 384) sConst[OB3 + tid - 256]  = b3[tid - 256];
    else if (tid < 448) sConst[OBC1 + tid - 384] = bc1[tid - 384];
    else if (tid < 480) sConst[OBC2 + tid - 448] = bc2[tid - 448];
    else                sConst[OWS + tid - 480]  = Ws[tid - 480];
    if (tid < 160)      sConst[OWS + 32 + tid]   = Ws[32 + tid];
    else if (tid < 192) sConst[OBS + tid - 160]  = bs[tid - 160];
    else if (tid < 224) sConst[OWC3 + tid - 192] = Wc3[tid - 192];
    else if (tid == 224) sConst[OBC3]            = bc3[0];

    bar_all();
    {
        const int r   = tid >> 3;
        const int j   = tid & 7;
        const int c0  = 46 * j;
        const int cnt = (j < 7) ? 46 : 43;
        const float* srow = stg + r * 365 + c0;
        bf16* xb = sXb + r * SX + c0;
        float s1 = 0.f, s2 = 0.f, s3 = 0.f, s4 = 0.f;
        float mn = 3.4e38f, mx = -3.4e38f;
#pragma unroll
        for (int i = 0; i < 46; ++i) {
            float v  = srow[i];
            bool ok  = (i < cnt);
            float vv = ok ? v : 0.0f;
            s1 += vv;
            float q = vv * vv;
            s2 += q; s3 += q * vv; s4 += q * q;
            mn = fminf(mn, ok ? v : 3.4e38f);
            mx = fmaxf(mx, ok ? v : -3.4e38f);
            xb[i] = (bf16)vv;
        }
#pragma unroll
        for (int m = 1; m < 8; m <<= 1) {
            s1 += __shfl_xor(s1, m); s2 += __shfl_xor(s2, m);
            s3 += __shfl_xor(s3, m); s4 += __shfl_xor(s4, m);
            mn = fminf(mn, __shfl_xor(mn, m));
            mx = fmaxf(mx, __shfl_xor(mx, m));
        }
        const float Tf = (float)T_DIM;
        float mu = s1 / Tf;
        float M2 = fmaxf(s2 - s1 * mu, 0.0f);
        float M3 = s3 - 3.f * mu * s2 + 2.f * Tf * mu * mu * mu;
        float M4 = s4 - 4.f * mu * s3 + 6.f * mu * mu * s2 - 3.f * Tf * mu * mu * mu * mu;
        float var = M2 / (Tf - 1.f);
        float sd  = sqrtf(var);
        float sk  = (M3 / Tf) / (sd * sd * sd + 1e-8f);
        float ku  = (M4 / Tf) / (var * var + 1e-8f);
        bar_lgkm();
#pragma unroll
        for (int cc = 0; cc < 4; ++cc) {
            int n = 4 * j + cc;
            float v = sConst[OBS + n]
                    + mu * sConst[OWS + 0*32+n] + sd * sConst[OWS + 1*32+n]
                    + mn * sConst[OWS + 2*32+n] + mx * sConst[OWS + 3*32+n]
                    + sk * sConst[OWS + 4*32+n] + ku * sConst[OWS + 5*32+n];
            sCB[r * SCB + 128 + n] = (bf16)v;
        }
    }
    bar_lgkm();

    const int l31   = lane & 31;
    const int lhalf = lane >> 5;

    // ---- L1 phase x20 (verbatim inner structure) ----
    for (int rep = 0; rep < 20; ++rep) {
        const bf16* bp1 = wt + WT1_OFF + (size_t)(2 * wv) * 11776 + (size_t)lane * 8;
        bf16x8 pf1[2][2];
#pragma unroll
        for (int d = 0; d < 2; ++d) {
            pf1[d][0] = *(const bf16x8*)(bp1 + d * 512);
            pf1[d][1] = *(const bf16x8*)(bp1 + 11776 + d * 512);
        }
        f32x16 a00 = z16(), a01 = z16(), a10 = z16(), a11 = z16();
        const bf16* ap0 = sXb + l31 * SX + lhalf * 8;
        const bf16* ap1 = sXb + (32 + l31) * SX + lhalf * 8;
#pragma unroll
        for (int ks = 0; ks < 23; ++ks) {
            bf16x8 fa0 = *(const bf16x8*)(ap0 + 16 * ks);
            bf16x8 fa1 = *(const bf16x8*)(ap1 + 16 * ks);
            bf16x8 w0 = pf1[ks & 1][0];
            bf16x8 w1 = pf1[ks & 1][1];
            if (ks + 2 < 23) {
                pf1[ks & 1][0] = *(const bf16x8*)(bp1 + (ks + 2) * 512);
                pf1[ks & 1][1] = *(const bf16x8*)(bp1 + 11776 + (ks + 2) * 512);
            }
            a00 = __builtin_amdgcn_mfma_f32_32x32x16_bf16(fa0, w0, a00, 0, 0, 0);
            a01 = __builtin_amdgcn_mfma_f32_32x32x16_bf16(fa0, w1, a01, 0, 0, 0);
            a10 = __builtin_amdgcn_mfma_f32_32x32x16_bf16(fa1, w0, a10, 0, 0, 0);
            a11 = __builtin_amdgcn_mfma_f32_32x32x16_bf16(fa1, w1, a11, 0, 0, 0);
        }
#pragma unroll
        for (int nt = 0; nt < 2; ++nt) {
            int col = 64 * wv + 32 * nt + l31;
            float bias = sConst[OB1 + col];
            const f32x16& am0 = nt ? a01 : a00;
            const f32x16& am1 = nt ? a11 : a10;
#pragma unroll
            for (int g = 0; g < 4; ++g) {
#pragma unroll
                for (int rr = 0; rr < 4; ++rr) {
                    int rowi = rr + 8 * g + 4 * lhalf;
                    sH1[rowi * SH1 + col]        = (bf16)fmaxf(am0[4 * g + rr] + bias, 0.0f);
                    sH1[(32 + rowi) * SH1 + col] = (bf16)fmaxf(am1[4 * g + rr] + bias, 0.0f);
                }
            }
        }
        bar_lgkm();
        dg += a00[0] + a01[5] + a10[10] + a11[15];
    }
    if (tid == 0) wtdig[4096 + blockIdx.x] = (bf16)dg;
}

// =====================================================================
// fused_mlp: BYTE-IDENTICAL to Round 4 (the timing reference).
// =====================================================================
__global__ __launch_bounds__(512, 2) void fused_mlp(
    const float* __restrict__ x, const bf16* __restrict__ wt,
    const float* __restrict__ b1, const float* __restrict__ b2, const float* __restrict__ b3,
    const float* __restrict__ Ws, const float* __restrict__ bs,
    const float* __restrict__ bc1, const float* __restrict__ bc2,
    const float* __restrict__ Wc3, const float* __restrict__ bc3,
    float* __restrict__ out)
{
    __shared__ __align__(16) char  sU[SU_BYTES];
    __shared__ __align__(16) bf16  sXb[ROWS * SX];
    __shared__ __align__(16) float sConst[NCONST];

    bf16*  sH1 = (bf16*)(sU + SU_H1);
    bf16*  sCB = (bf16*)(sU + SU_CB);
    float* sC2 = (float*)(sU + SU_C2);
    float* stg = (float*)sU;

    const int tid  = threadIdx.x;
    const int lane = tid & 63;
    const int wv   = tid >> 6;
    const int row0 = blockIdx.x * ROWS;

    const float* xt = x + (size_t)row0 * T_DIM;
    {
#pragma unroll
        for (int i = 0; i < 12; ++i) {
            int s = i * 8 + wv;
            if (s < 91) {
                stage16(xt + s * 256 + lane * 4, (void*)(sU + (size_t)s * 1024));
            } else if (s == 91) {
                if (lane < 16)
                    stage16(xt + s * 256 + lane * 4, (void*)(sU + (size_t)s * 1024));
            }
        }
    }
    const bf16* bp1 = wt + WT1_OFF + (size_t)(2 * wv) * 11776 + (size_t)lane * 8;
    bf16x8 pf1[2][2];
#pragma unroll
    for (int d = 0; d < 2; ++d) {
        pf1[d][0] = *(const bf16x8*)(bp1 + d * 512);
        pf1[d][1] = *(const bf16x8*)(bp1 + 11776 + d * 512);
    }
    sConst[OB1 + tid] = b1[tid];
    if (tid < 256)      sConst[OB2 + tid]        = b2[tid];
    else if (tid < 384) sConst[OB3 + tid - 256]  = b3[tid - 256];
    else if (tid < 448) sConst[OBC1 + tid - 384] = bc1[tid - 384];
    else if (tid < 480) sConst[OBC2 + tid - 448] = bc2[tid - 448];
    else                sConst[OWS + tid - 480]  = Ws[tid - 480];
    if (tid < 160)      sConst[OWS + 32 + tid]   = Ws[32 + tid];
    else if (tid < 192) sConst[OBS + tid - 160]  = bs[tid - 160];
    else if (tid < 224) sConst[OWC3 + tid - 192] = Wc3[tid - 192];
    else if (tid == 224) sConst[OBC3]            = bc3[0];

    bar_all();

    {
        const int r   = tid >> 3;
        const int j   = tid & 7;
        const int c0  = 46 * j;
        const int cnt = (j < 7) ? 46 : 43;
        const float* srow = stg + r * 365 + c0;
        bf16* xb = sXb + r * SX + c0;
        float s1 = 0.f, s2 = 0.f, s3 = 0.f, s4 = 0.f;
        float mn = 3.4e38f, mx = -3.4e38f;
#pragma unroll
        for (int i = 0; i < 46; ++i) {
            float v  = srow[i];
            bool ok  = (i < cnt);
            float vv = ok ? v : 0.0f;
            s1 += vv;
            float q = vv * vv;
            s2 += q; s3 += q * vv; s4 += q * q;
            mn = fminf(mn, ok ? v : 3.4e38f);
            mx = fmaxf(mx, ok ? v : -3.4e38f);
            xb[i] = (bf16)vv;
        }
#pragma unroll
        for (int m = 1; m < 8; m <<= 1) {
            s1 += __shfl_xor(s1, m); s2 += __shfl_xor(s2, m);
            s3 += __shfl_xor(s3, m); s4 += __shfl_xor(s4, m);
            mn = fminf(mn, __shfl_xor(mn, m));
            mx = fmaxf(mx, __shfl_xor(mx, m));
        }
        const float Tf = (float)T_DIM;
        float mu = s1 / Tf;
        float M2 = fmaxf(s2 - s1 * mu, 0.0f);
        float M3 = s3 - 3.f * mu * s2 + 2.f * Tf * mu * mu * mu;
        float M4 = s4 - 4.f * mu * s3 + 6.f * mu * mu * s2 - 3.f * Tf * mu * mu * mu * mu;
        float var = M2 / (Tf - 1.f);
        float sd  = sqrtf(var);
        float sk  = (M3 / Tf) / (sd * sd * sd + 1e-8f);
        float ku  = (M4 / Tf) / (var * var + 1e-8f);

        bar_lgkm();

#pragma unroll
        for (int cc = 0; cc < 4; ++cc) {
            int n = 4 * j + cc;
            float v = sConst[OBS + n]
                    + mu * sConst[OWS + 0*32+n] + sd * sConst[OWS + 1*32+n]
                    + mn * sConst[OWS + 2*32+n] + mx * sConst[OWS + 3*32+n]
                    + sk * sConst[OWS + 4*32+n] + ku * sConst[OWS + 5*32+n];
            sCB[r * SCB + 128 + n] = (bf16)v;
        }
    }

    const int l31   = lane & 31;
    const int lhalf = lane >> 5;

    const bf16* bp2 = wt + WT2_OFF + (size_t)wv * 16384 + (size_t)lane * 8;
    bf16x8 pf2[4];
    {
        f32x16 a00 = z16(), a01 = z16(), a10 = z16(), a11 = z16();
        const bf16* ap0 = sXb + l31 * SX + lhalf * 8;
        const bf16* ap1 = sXb + (32 + l31) * SX + lhalf * 8;
#pragma unroll
        for (int ks = 0; ks < 23; ++ks) {
            bf16x8 fa0 = *(const bf16x8*)(ap0 + 16 * ks);
            bf16x8 fa1 = *(const bf16x8*)(ap1 + 16 * ks);
            bf16x8 w0 = pf1[ks & 1][0];
            bf16x8 w1 = pf1[ks & 1][1];
            if (ks + 2 < 23) {
                pf1[ks & 1][0] = *(const bf16x8*)(bp1 + (ks + 2) * 512);
                pf1[ks & 1][1] = *(const bf16x8*)(bp1 + 11776 + (ks + 2) * 512);
            }
            a00 = __builtin_amdgcn_mfma_f32_32x32x16_bf16(fa0, w0, a00, 0, 0, 0);
            a01 = __builtin_amdgcn_mfma_f32_32x32x16_bf16(fa0, w1, a01, 0, 0, 0);
            a10 = __builtin_amdgcn_mfma_f32_32x32x16_bf16(fa1, w0, a10, 0, 0, 0);
            a11 = __builtin_amdgcn_mfma_f32_32x32x16_bf16(fa1, w1, a11, 0, 0, 0);
        }
#pragma unroll
        for (int d = 0; d < 4; ++d)
            pf2[d] = *(const bf16x8*)(bp2 + d * 512);
#pragma unroll
        for (int nt = 0; nt < 2; ++nt) {
            int col = 64 * wv + 32 * nt + l31;
            float bias = sConst[OB1 + col];
            const f32x16& am0 = nt ? a01 : a00;
            const f32x16& am1 = nt ? a11 : a10;
#pragma unroll
            for (int g = 0; g < 4; ++g) {
#pragma unroll
                for (int rr = 0; rr < 4; ++rr) {
                    int rowi = rr + 8 * g + 4 * lhalf;
                    sH1[rowi * SH1 + col]        = (bf16)fmaxf(am0[4 * g + rr] + bias, 0.0f);
                    sH1[(32 + rowi) * SH1 + col] = (bf16)fmaxf(am1[4 * g + rr] + bias, 0.0f);
                }
            }
        }
    }
    bar_lgkm();

    const bf16* bp3 = wt + WT3_OFF + (size_t)(wv & 3) * 8192 + (size_t)lane * 8;
    bf16x8 pf3[4];
    {
        f32x16 ac0 = z16(), ac1 = z16();
        const bf16* ap0 = sH1 + l31 * SH1 + lhalf * 8;
        const bf16* ap1 = sH1 + (32 + l31) * SH1 + lhalf * 8;
#pragma unroll
        for (int ks = 0; ks < 32; ++ks) {
            bf16x8 fa0 = *(const bf16x8*)(ap0 + 16 * ks);
            bf16x8 fa1 = *(const bf16x8*)(ap1 + 16 * ks);
            bf16x8 w = pf2[ks & 3];
            if (ks + 4 < 32)
                pf2[ks & 3] = *(const bf16x8*)(bp2 + (ks + 4) * 512);
            ac0 = __builtin_amdgcn_mfma_f32_32x32x16_bf16(fa0, w, ac0, 0, 0, 0);
            ac1 = __builtin_amdgcn_mfma_f32_32x32x16_bf16(fa1, w, ac1, 0, 0, 0);
        }
#pragma unroll
        for (int d = 0; d < 4; ++d)
            pf3[d] = *(const bf16x8*)(bp3 + d * 512);
        bf16* H2 = sXb;
        int col = 32 * wv + l31;
        float bias = sConst[OB2 + col];
#pragma unroll
        for (int g = 0; g < 4; ++g) {
#pragma unroll
            for (int rr = 0; rr < 4; ++rr) {
                int rowi = rr + 8 * g + 4 * lhalf;
                H2[rowi * SH2 + col]        = (bf16)fmaxf(ac0[4 * g + rr] + bias, 0.0f);
                H2[(32 + rowi) * SH2 + col] = (bf16)fmaxf(ac1[4 * g + rr] + bias, 0.0f);
            }
        }
    }
    bar_lgkm();

    const bf16* bpc1 = wt + WTC1_OFF + (size_t)(wv >> 2) * 5120 + (size_t)lane * 8;
    bf16x8 w0c[5], w1c[5];
    {
        const int ct = wv & 3;
        const int m3 = wv >> 2;
        f32x16 acc = z16();
        const bf16* H2 = sXb;
        const bf16* ap = H2 + (32 * m3 + l31) * SH2 + lhalf * 8;
#pragma unroll
        for (int ks = 0; ks < 16; ++ks) {
            bf16x8 a = *(const bf16x8*)(ap + 16 * ks);
            bf16x8 w = pf3[ks & 3];
            if (ks + 4 < 16)
                pf3[ks & 3] = *(const bf16x8*)(bp3 + (ks + 4) * 512);
            acc = __builtin_amdgcn_mfma_f32_32x32x16_bf16(a, w, acc, 0, 0, 0);
        }
#pragma unroll
        for (int ks = 0; ks < 5; ++ks) {
            w0c[ks] = *(const bf16x8*)(bpc1 + ks * 512);
            w1c[ks] = *(const bf16x8*)(bpc1 + 2560 + ks * 512);
        }
        int col = 32 * ct + l31;
        float bias = sConst[OB3 + col];
#pragma unroll
        for (int g = 0; g < 4; ++g) {
#pragma unroll
            for (int rr = 0; rr < 4; ++rr) {
                int rowi = 32 * m3 + rr + 8 * g + 4 * lhalf;
                sCB[rowi * SCB + col] = (bf16)fmaxf(acc[4 * g + rr] + bias, 0.0f);
            }
        }
    }
    bar_lgkm();

    const bf16* bpc2 = wt + WTC2_OFF + (size_t)(wv >> 2) * 1024 + (size_t)lane * 8;
    bf16x8 wc2[2];
    {
        const int l15 = lane & 15;
        const int lq  = lane >> 4;
        const int mt  = wv & 3;
        const int g2  = wv >> 2;
        f32x4 ac0 = z4(), ac1 = z4();
        const bf16* ap = sCB + (16 * mt + l15) * SCB + lq * 8;
        bf16x8 av[5];
#pragma unroll
        for (int ks = 0; ks < 5; ++ks)
            av[ks] = *(const bf16x8*)(ap + 32 * ks);
#pragma unroll
        for (int ks = 0; ks < 5; ++ks) {
            ac0 = __builtin_amdgcn_mfma_f32_16x16x32_bf16(av[ks], w0c[ks], ac0, 0, 0, 0);
            ac1 = __builtin_amdgcn_mfma_f32_16x16x32_bf16(av[ks], w1c[ks], ac1, 0, 0, 0);
        }
#pragma unroll
        for (int ks = 0; ks < 2; ++ks)
            wc2[ks] = *(const bf16x8*)(bpc2 + ks * 512);
        bf16* C1 = sH1;
#pragma unroll
        for (int nt = 0; nt < 2; ++nt) {
            int col = 16 * (2 * g2 + nt) + l15;
            float bias = sConst[OBC1 + col];
            const f32x4& ac = nt ? ac1 : ac0;
#pragma unroll
            for (int reg = 0; reg < 4; ++reg) {
                int m = 16 * mt + lq * 4 + reg;
                C1[m * SC1 + col] = (bf16)fmaxf(ac[reg] + bias, 0.0f);
            }
        }
    }
    bar_lgkm();

    {
        const int l15 = lane & 15;
        const int lq  = lane >> 4;
        const int mt  = wv & 3;
        const int nt2 = wv >> 2;
        f32x4 acc = z4();
        const bf16* C1 = sH1;
        const bf16* ap = C1 + (16 * mt + l15) * SC1 + lq * 8;
        bf16x8 av[2];
#pragma unroll
        for (int ks = 0; ks < 2; ++ks)
            av[ks] = *(const bf16x8*)(ap + 32 * ks);
#pragma unroll
        for (int ks = 0; ks < 2; ++ks)
            acc = __builtin_amdgcn_mfma_f32_16x16x32_bf16(av[ks], wc2[ks], acc, 0, 0, 0);
        int col = 16 * nt2 + l15;
        float bias = sConst[OBC2 + col];
#pragma unroll
        for (int reg = 0; reg < 4; ++reg) {
            int m = 16 * mt + lq * 4 + reg;
            sC2[m * SC2 + col] = fmaxf(acc[reg] + bias, 0.0f);
        }
    }
    bar_lgkm();

    if (tid < ROWS) {
        const float* c2r = sC2 + tid * SC2;
        float z = sConst[OBC3];
#pragma unroll
        for (int k = 0; k < 32; ++k) z += c2r[k] * sConst[OWC3 + k];
        float sg = 1.0f / (1.0f + __expf(-z));
        out[row0 + tid] = sg * 4.0f + 6.0f;
    }
}

extern "C" void kernel_launch(void* const* d_in, const int* in_sizes, int n_in,
                              void* d_out, int out_size, void* d_ws, size_t ws_size,
                              hipStream_t stream) {
    const float* x   = (const float*)d_in[0];
    const float* W1  = (const float*)d_in[1];
    const float* b1  = (const float*)d_in[2];
    const float* W2  = (const float*)d_in[3];
    const float* b2  = (const float*)d_in[4];
    const float* W3  = (const float*)d_in[5];
    const float* b3  = (const float*)d_in[6];
    const float* Ws  = (const float*)d_in[7];
    const float* bs  = (const float*)d_in[8];
    const float* Wc1 = (const float*)d_in[9];
    const float* bc1 = (const float*)d_in[10];
    const float* Wc2 = (const float*)d_in[11];
    const float* bc2 = (const float*)d_in[12];
    const float* Wc3 = (const float*)d_in[13];
    const float* bc3 = (const float*)d_in[14];
    float* out = (float*)d_out;
    bf16* wt = (bf16*)d_ws;

    const int B = in_sizes[0] / T_DIM;          // 65536

    // Ablation dispatches (digests land in wt region; prep_weights overwrites after)
    abl_phaseA<<<B / ROWS, 512, 0, stream>>>(x, wt, b1, b2, b3, Ws, bs, bc1, bc2, Wc3, bc3);
    abl_L1<<<B / ROWS, 512, 0, stream>>>(x, wt, b1, b2, b3, Ws, bs, bc1, bc2, Wc3, bc3, wt);

    prep_weights<<<(WTOTAL + 255) / 256, 256, 0, stream>>>(W1, W2, W3, Wc1, Wc2, wt);
    fused_mlp<<<B / ROWS, 512, 0, stream>>>(x, wt, b1, b2, b3, Ws, bs, bc1, bc2, Wc3, bc3, out);
}

// Round 6
// 229.366 us; speedup vs baseline: 3.5208x; 3.5208x over previous
//
#include <hip/hip_runtime.h>
#include <stdint.h>
#include <stddef.h>

typedef __bf16 bf16;
typedef bf16 bf16x4 __attribute__((ext_vector_type(4)));
typedef bf16 bf16x8 __attribute__((ext_vector_type(8)));
typedef float f32x4 __attribute__((ext_vector_type(4)));
typedef float f32x16 __attribute__((ext_vector_type(16)));

#define T_DIM 365
#define SX    376      // LDS stride (bf16) for Xb
#define SH1   520
#define SH2   264
#define SCB   184      // combined: 128 seq + 32 stat
#define SC1   72
#define SC2   33

#define ROWS  64

// Union region: fp32 x staging (Phase A) aliased over sH1 / sCB / sC2.
#define SU_H1    0
#define SU_CB    66560
#define SU_C2    90112
#define SU_BYTES 98816

// ws element offsets (bf16 elements) — fragment-major packed layouts (UNCHANGED).
#define WT1_OFF  0
#define WT2_OFF  188416
#define WT3_OFF  319488
#define WTC1_OFF 352256
#define WTC2_OFF 362496
#define WTOTAL   364544

// sConst float offsets
#define OB1   0
#define OB2   512
#define OB3   768
#define OBC1  896
#define OBC2  960
#define OWS   992
#define OBS   1184
#define OWC3  1216
#define OBC3  1248
#define NCONST 1252

__global__ void prep_weights(const float* __restrict__ W1, const float* __restrict__ W2,
                             const float* __restrict__ W3, const float* __restrict__ Wc1,
                             const float* __restrict__ Wc2, bf16* __restrict__ ws) {
    int idx = blockIdx.x * 256 + threadIdx.x;
    if (idx >= WTOTAL) return;
    if (idx < WT2_OFF) {
        int t = idx;
        int j = t & 7, lane = (t >> 3) & 63, f = t >> 9;
        int ks = f % 23; f /= 23;
        int nt = f & 3, wv = f >> 2;
        int n = 128 * wv + 32 * nt + (lane & 31);
        int k = 16 * ks + (lane >> 5) * 8 + j;
        ws[idx] = (k < T_DIM) ? (bf16)W1[k * 512 + n] : (bf16)0.0f;
    } else if (idx < WT3_OFF) {
        int t = idx - WT2_OFF;
        int j = t & 7, lane = (t >> 3) & 63, f = t >> 9;
        int ks = f & 31; f >>= 5;
        int nt = f & 1, wv = f >> 1;
        int n = 64 * wv + 32 * nt + (lane & 31);
        int k = 16 * ks + (lane >> 5) * 8 + j;
        ws[idx] = (bf16)W2[k * 256 + n];
    } else if (idx < WTC1_OFF) {
        int t = idx - WT3_OFF;
        int j = t & 7, lane = (t >> 3) & 63, f = t >> 9;
        int ks = f & 15, wv = f >> 4;
        int n = 32 * wv + (lane & 31);
        int k = 16 * ks + (lane >> 5) * 8 + j;
        ws[idx] = (bf16)W3[k * 128 + n];
    } else if (idx < WTC2_OFF) {
        int t = idx - WTC1_OFF;
        int j = t & 7, lane = (t >> 3) & 63, f = t >> 9;
        int ks = f % 5; f /= 5;
        int nt = f & 1, g = f >> 1;
        int n = 16 * (2 * g + nt) + (lane & 15);
        int k = 32 * ks + (lane >> 4) * 8 + j;
        ws[idx] = (bf16)Wc1[k * 64 + n];
    } else {
        int t = idx - WTC2_OFF;
        int j = t & 7, lane = (t >> 3) & 63, f = t >> 9;
        int ks = f & 1, nt = f >> 1;
        int n = 16 * nt + (lane & 15);
        int k = 32 * ks + (lane >> 4) * 8 + j;
        ws[idx] = (bf16)Wc2[k * 32 + n];
    }
}

__device__ inline f32x16 z16() {
    f32x16 v;
#pragma unroll
    for (int i = 0; i < 16; ++i) v[i] = 0.0f;
    return v;
}
__device__ inline f32x4 z4() {
    f32x4 v;
#pragma unroll
    for (int i = 0; i < 4; ++i) v[i] = 0.0f;
    return v;
}

// LDS-visibility barrier (no vmcnt drain — keeps global prefetches in flight)
__device__ __forceinline__ void bar_lgkm() {
    asm volatile("s_waitcnt lgkmcnt(0)" ::: "memory");
    __builtin_amdgcn_s_barrier();
}
// Full barrier (after global_load_lds staging)
__device__ __forceinline__ void bar_all() {
    asm volatile("s_waitcnt vmcnt(0) lgkmcnt(0)" ::: "memory");
    __builtin_amdgcn_s_barrier();
}

__device__ __forceinline__ void stage16(const float* g, void* ldsbase) {
    __builtin_amdgcn_global_load_lds(
        (const __attribute__((address_space(1))) void*)g,
        (__attribute__((address_space(3))) void*)ldsbase, 16, 0, 0);
}

__global__ __launch_bounds__(512, 2) void fused_mlp(
    const float* __restrict__ x, const bf16* __restrict__ wt,
    const float* __restrict__ b1, const float* __restrict__ b2, const float* __restrict__ b3,
    const float* __restrict__ Ws, const float* __restrict__ bs,
    const float* __restrict__ bc1, const float* __restrict__ bc2,
    const float* __restrict__ Wc3, const float* __restrict__ bc3,
    float* __restrict__ out)
{
    __shared__ __align__(16) char  sU[SU_BYTES];   // staging | {sH1, sCB, sC2}
    __shared__ __align__(16) bf16  sXb[ROWS * SX]; // Xb bf16; reused as H2 [64][SH2]
    __shared__ __align__(16) float sConst[NCONST];

    bf16*  sH1 = (bf16*)(sU + SU_H1);
    bf16*  sCB = (bf16*)(sU + SU_CB);
    float* sC2 = (float*)(sU + SU_C2);
    float* stg = (float*)sU;

    const int tid  = threadIdx.x;
    const int lane = tid & 63;
    const int wv   = tid >> 6;        // 0..7
    const int row0 = blockIdx.x * ROWS;

    // ================= A1: issue x staging + L1 weight prefetch + consts ==========
    const float* xt = x + (size_t)row0 * T_DIM;   // 64*1460B region, 16B-aligned
    {
        // 92 dwordx4 wave-instructions total: slot s = i*8 + wv
#pragma unroll
        for (int i = 0; i < 12; ++i) {
            int s = i * 8 + wv;
            if (s < 91) {
                stage16(xt + s * 256 + lane * 4, (void*)(sU + (size_t)s * 1024));
            } else if (s == 91) {
                if (lane < 16)
                    stage16(xt + s * 256 + lane * 4, (void*)(sU + (size_t)s * 1024));
            }
        }
    }
    // L1 re-tiling: wave = (rt = wv&1 row-tile, cq = wv>>1 col-quad of 4x32 cols)
    const int rt1 = wv & 1;
    const int cq1 = wv >> 1;
    const bf16* bp1 = wt + WT1_OFF + (size_t)(4 * cq1) * 11776 + (size_t)lane * 8;
    bf16x8 pf1[2][4];
#pragma unroll
    for (int d = 0; d < 2; ++d)
#pragma unroll
        for (int q = 0; q < 4; ++q)
            pf1[d][q] = *(const bf16x8*)(bp1 + (size_t)q * 11776 + d * 512);
    // const staging
    sConst[OB1 + tid] = b1[tid];
    if (tid < 256)      sConst[OB2 + tid]        = b2[tid];
    else if (tid < 384) sConst[OB3 + tid - 256]  = b3[tid - 256];
    else if (tid < 448) sConst[OBC1 + tid - 384] = bc1[tid - 384];
    else if (tid < 480) sConst[OBC2 + tid - 448] = bc2[tid - 448];
    else                sConst[OWS + tid - 480]  = Ws[tid - 480];
    if (tid < 160)      sConst[OWS + 32 + tid]   = Ws[32 + tid];
    else if (tid < 192) sConst[OBS + tid - 160]  = bs[tid - 160];
    else if (tid < 224) sConst[OWC3 + tid - 192] = Wc3[tid - 192];
    else if (tid == 224) sConst[OBC3]            = bc3[0];

    bar_all();   // staging + consts visible to all waves

    // ================= A2: stats + Xb bf16 from LDS staging (48-col segments) =====
    {
        const int r   = tid >> 3;          // row 0..63
        const int j   = tid & 7;           // 8 threads per row
        const int c0  = 48 * j;            // 16B-aligned bf16 segment start
        const int cnt = (j < 7) ? 48 : (T_DIM - 336);   // j==7: 29 valid cols
        const float* srow = stg + r * 365 + c0;
        bf16* xb = sXb + r * SX + c0;
        float s1 = 0.f, s2 = 0.f, s3 = 0.f, s4 = 0.f;
        float mn = 3.4e38f, mx = -3.4e38f;
        const int nw = (j < 7) ? 6 : 5;    // b128 writes (j==7 stops at col 375)
#pragma unroll
        for (int w8 = 0; w8 < 6; ++w8) {
            bf16x8 pk;
#pragma unroll
            for (int e = 0; e < 8; ++e) {
                int i = 8 * w8 + e;
                float v  = srow[i];        // in-bounds of sU even when i>=cnt
                bool ok  = (i < cnt);
                float vv = ok ? v : 0.0f;
                s1 += vv;
                float q = vv * vv;
                s2 += q; s3 += q * vv; s4 += q * q;
                mn = fminf(mn, ok ? v : 3.4e38f);
                mx = fmaxf(mx, ok ? v : -3.4e38f);
                pk[e] = (bf16)vv;
            }
            if (w8 < nw) *(bf16x8*)(xb + 8 * w8) = pk;
        }
#pragma unroll
        for (int m = 1; m < 8; m <<= 1) {
            s1 += __shfl_xor(s1, m); s2 += __shfl_xor(s2, m);
            s3 += __shfl_xor(s3, m); s4 += __shfl_xor(s4, m);
            mn = fminf(mn, __shfl_xor(mn, m));
            mx = fmaxf(mx, __shfl_xor(mx, m));
        }
        const float Tf = (float)T_DIM;
        float mu = s1 / Tf;
        float M2 = fmaxf(s2 - s1 * mu, 0.0f);
        float M3 = s3 - 3.f * mu * s2 + 2.f * Tf * mu * mu * mu;
        float M4 = s4 - 4.f * mu * s3 + 6.f * mu * mu * s2 - 3.f * Tf * mu * mu * mu * mu;
        float var = M2 / (Tf - 1.f);
        float sd  = sqrtf(var);
        float sk  = (M3 / Tf) / (sd * sd * sd + 1e-8f);
        float ku  = (M4 / Tf) / (var * var + 1e-8f);

        bar_lgkm();  // all staging reads done before statfeat overwrites stg region

        // A3: stat features -> sCB cols 128..159 (aliases staging region: safe now)
#pragma unroll
        for (int cc = 0; cc < 4; ++cc) {
            int n = 4 * j + cc;
            float v = sConst[OBS + n]
                    + mu * sConst[OWS + 0*32+n] + sd * sConst[OWS + 1*32+n]
                    + mn * sConst[OWS + 2*32+n] + mx * sConst[OWS + 3*32+n]
                    + sk * sConst[OWS + 4*32+n] + ku * sConst[OWS + 5*32+n];
            sCB[r * SCB + 128 + n] = (bf16)v;
        }
    }

    const int l31   = lane & 31;
    const int lhalf = lane >> 5;

    // ================= Layer 1: [64,368] x [368,512] -> H1 ========================
    // wave = 1 row-tile x 4 col-tiles: 1 fa read feeds 4 MFMA (A-LDS traffic halved)
    const int rt2 = wv & 1;
    const int cp2 = wv >> 1;
    const bf16* bp2 = wt + WT2_OFF + (size_t)(2 * cp2) * 16384 + (size_t)lane * 8;
    bf16x8 pf2[2][2];
    {
        f32x16 acc[4] = { z16(), z16(), z16(), z16() };
        const bf16* ap = sXb + (32 * rt1 + l31) * SX + lhalf * 8;
#pragma unroll
        for (int ks = 0; ks < 23; ++ks) {
            bf16x8 fa = *(const bf16x8*)(ap + 16 * ks);
            bf16x8 w[4];
#pragma unroll
            for (int q = 0; q < 4; ++q) w[q] = pf1[ks & 1][q];
            if (ks + 2 < 23) {
#pragma unroll
                for (int q = 0; q < 4; ++q)
                    pf1[ks & 1][q] = *(const bf16x8*)(bp1 + (size_t)q * 11776 + (ks + 2) * 512);
            }
#pragma unroll
            for (int q = 0; q < 4; ++q)
                acc[q] = __builtin_amdgcn_mfma_f32_32x32x16_bf16(fa, w[q], acc[q], 0, 0, 0);
        }
        // prefetch L2 prologue before the barrier (stays in flight across it)
#pragma unroll
        for (int d = 0; d < 2; ++d)
#pragma unroll
            for (int q = 0; q < 2; ++q)
                pf2[d][q] = *(const bf16x8*)(bp2 + (size_t)q * 16384 + d * 512);
#pragma unroll
        for (int q = 0; q < 4; ++q) {
            int col = 128 * cq1 + 32 * q + l31;
            float bias = sConst[OB1 + col];
#pragma unroll
            for (int g = 0; g < 4; ++g) {
#pragma unroll
                for (int rr = 0; rr < 4; ++rr) {
                    int rowi = 32 * rt1 + rr + 8 * g + 4 * lhalf;
                    sH1[rowi * SH1 + col] = (bf16)fmaxf(acc[q][4 * g + rr] + bias, 0.0f);
                }
            }
        }
    }
    bar_lgkm();

    // ================= Layer 2: [64,512] x [512,256] -> H2 (in sXb) ===============
    // wave = 1 row-tile x 2 col-tiles: 1 fa read feeds 2 MFMA (A-LDS traffic halved)
    const bf16* bp3 = wt + WT3_OFF + (size_t)(wv & 3) * 8192 + (size_t)lane * 8;
    bf16x8 pf3[4];
    {
        f32x16 acc[2] = { z16(), z16() };
        const bf16* ap = sH1 + (32 * rt2 + l31) * SH1 + lhalf * 8;
#pragma unroll
        for (int ks = 0; ks < 32; ++ks) {
            bf16x8 fa = *(const bf16x8*)(ap + 16 * ks);
            bf16x8 w0 = pf2[ks & 1][0];
            bf16x8 w1 = pf2[ks & 1][1];
            if (ks + 2 < 32) {
                pf2[ks & 1][0] = *(const bf16x8*)(bp2 + (ks + 2) * 512);
                pf2[ks & 1][1] = *(const bf16x8*)(bp2 + 16384 + (ks + 2) * 512);
            }
            acc[0] = __builtin_amdgcn_mfma_f32_32x32x16_bf16(fa, w0, acc[0], 0, 0, 0);
            acc[1] = __builtin_amdgcn_mfma_f32_32x32x16_bf16(fa, w1, acc[1], 0, 0, 0);
        }
        // prefetch L3 prologue
#pragma unroll
        for (int d = 0; d < 4; ++d)
            pf3[d] = *(const bf16x8*)(bp3 + d * 512);
        bf16* H2 = sXb;
#pragma unroll
        for (int q = 0; q < 2; ++q) {
            int col = 64 * cp2 + 32 * q + l31;
            float bias = sConst[OB2 + col];
#pragma unroll
            for (int g = 0; g < 4; ++g) {
#pragma unroll
                for (int rr = 0; rr < 4; ++rr) {
                    int rowi = 32 * rt2 + rr + 8 * g + 4 * lhalf;
                    H2[rowi * SH2 + col] = (bf16)fmaxf(acc[q][4 * g + rr] + bias, 0.0f);
                }
            }
        }
    }
    bar_lgkm();

    // ================= Layer 3: [64,256] x [256,128] -> seq (sCB 0..127) ==========
    const bf16* bpc1 = wt + WTC1_OFF + (size_t)(wv >> 2) * 5120 + (size_t)lane * 8;
    bf16x8 w0c[5], w1c[5];
    {
        const int ct = wv & 3;
        const int m3 = wv >> 2;
        f32x16 acc = z16();
        const bf16* H2 = sXb;
        const bf16* ap = H2 + (32 * m3 + l31) * SH2 + lhalf * 8;
#pragma unroll
        for (int ks = 0; ks < 16; ++ks) {
            bf16x8 a = *(const bf16x8*)(ap + 16 * ks);
            bf16x8 w = pf3[ks & 3];
            if (ks + 4 < 16)
                pf3[ks & 3] = *(const bf16x8*)(bp3 + (ks + 4) * 512);
            acc = __builtin_amdgcn_mfma_f32_32x32x16_bf16(a, w, acc, 0, 0, 0);
        }
        // prefetch c1 weights
#pragma unroll
        for (int ks = 0; ks < 5; ++ks) {
            w0c[ks] = *(const bf16x8*)(bpc1 + ks * 512);
            w1c[ks] = *(const bf16x8*)(bpc1 + 2560 + ks * 512);
        }
        int col = 32 * ct + l31;
        float bias = sConst[OB3 + col];
#pragma unroll
        for (int g = 0; g < 4; ++g) {
#pragma unroll
            for (int rr = 0; rr < 4; ++rr) {
                int rowi = 32 * m3 + rr + 8 * g + 4 * lhalf;
                sCB[rowi * SCB + col] = (bf16)fmaxf(acc[4 * g + rr] + bias, 0.0f);
            }
        }
    }
    bar_lgkm();

    // ================= c1: [64,160] x [160,64] -> C1 (16x16x32) ===================
    const bf16* bpc2 = wt + WTC2_OFF + (size_t)(wv >> 2) * 1024 + (size_t)lane * 8;
    bf16x8 wc2[2];
    {
        const int l15 = lane & 15;
        const int lq  = lane >> 4;
        const int mt  = wv & 3;
        const int g2  = wv >> 2;
        f32x4 ac0 = z4(), ac1 = z4();
        const bf16* ap = sCB + (16 * mt + l15) * SCB + lq * 8;
        bf16x8 av[5];
#pragma unroll
        for (int ks = 0; ks < 5; ++ks)
            av[ks] = *(const bf16x8*)(ap + 32 * ks);
#pragma unroll
        for (int ks = 0; ks < 5; ++ks) {
            ac0 = __builtin_amdgcn_mfma_f32_16x16x32_bf16(av[ks], w0c[ks], ac0, 0, 0, 0);
            ac1 = __builtin_amdgcn_mfma_f32_16x16x32_bf16(av[ks], w1c[ks], ac1, 0, 0, 0);
        }
        // prefetch c2 weights
#pragma unroll
        for (int ks = 0; ks < 2; ++ks)
            wc2[ks] = *(const bf16x8*)(bpc2 + ks * 512);
        bf16* C1 = sH1;
#pragma unroll
        for (int nt = 0; nt < 2; ++nt) {
            int col = 16 * (2 * g2 + nt) + l15;
            float bias = sConst[OBC1 + col];
            const f32x4& ac = nt ? ac1 : ac0;
#pragma unroll
            for (int reg = 0; reg < 4; ++reg) {
                int m = 16 * mt + lq * 4 + reg;
                C1[m * SC1 + col] = (bf16)fmaxf(ac[reg] + bias, 0.0f);
            }
        }
    }
    bar_lgkm();

    // ================= c2: [64,64] x [64,32] -> sC2 (f32) =========================
    {
        const int l15 = lane & 15;
        const int lq  = lane >> 4;
        const int mt  = wv & 3;
        const int nt2 = wv >> 2;
        f32x4 acc = z4();
        const bf16* C1 = sH1;
        const bf16* ap = C1 + (16 * mt + l15) * SC1 + lq * 8;
        bf16x8 av[2];
#pragma unroll
        for (int ks = 0; ks < 2; ++ks)
            av[ks] = *(const bf16x8*)(ap + 32 * ks);
#pragma unroll
        for (int ks = 0; ks < 2; ++ks)
            acc = __builtin_amdgcn_mfma_f32_16x16x32_bf16(av[ks], wc2[ks], acc, 0, 0, 0);
        int col = 16 * nt2 + l15;
        float bias = sConst[OBC2 + col];
#pragma unroll
        for (int reg = 0; reg < 4; ++reg) {
            int m = 16 * mt + lq * 4 + reg;
            sC2[m * SC2 + col] = fmaxf(acc[reg] + bias, 0.0f);
        }
    }
    bar_lgkm();

    // ================= final: 32 -> 1 dot, sigmoid*4+6 ============================
    if (tid < ROWS) {
        const float* c2r = sC2 + tid * SC2;
        float z = sConst[OBC3];
#pragma unroll
        for (int k = 0; k < 32; ++k) z += c2r[k] * sConst[OWC3 + k];
        float sg = 1.0f / (1.0f + __expf(-z));
        out[row0 + tid] = sg * 4.0f + 6.0f;
    }
}

extern "C" void kernel_launch(void* const* d_in, const int* in_sizes, int n_in,
                              void* d_out, int out_size, void* d_ws, size_t ws_size,
                              hipStream_t stream) {
    const float* x   = (const float*)d_in[0];
    const float* W1  = (const float*)d_in[1];
    const float* b1  = (const float*)d_in[2];
    const float* W2  = (const float*)d_in[3];
    const float* b2  = (const float*)d_in[4];
    const float* W3  = (const float*)d_in[5];
    const float* b3  = (const float*)d_in[6];
    const float* Ws  = (const float*)d_in[7];
    const float* bs  = (const float*)d_in[8];
    const float* Wc1 = (const float*)d_in[9];
    const float* bc1 = (const float*)d_in[10];
    const float* Wc2 = (const float*)d_in[11];
    const float* bc2 = (const float*)d_in[12];
    const float* Wc3 = (const float*)d_in[13];
    const float* bc3 = (const float*)d_in[14];
    float* out = (float*)d_out;
    bf16* wt = (bf16*)d_ws;

    const int B = in_sizes[0] / T_DIM;          // 65536
    prep_weights<<<(WTOTAL + 255) / 256, 256, 0, stream>>>(W1, W2, W3, Wc1, Wc2, wt);
    fused_mlp<<<B / ROWS, 512, 0, stream>>>(x, wt, b1, b2, b3, Ws, bs, bc1, bc2, Wc3, bc3, out);
}

// Round 7
// 223.149 us; speedup vs baseline: 3.6189x; 1.0279x over previous
//
#include <hip/hip_runtime.h>
#include <stdint.h>
#include <stddef.h>

typedef __bf16 bf16;
typedef bf16 bf16x4 __attribute__((ext_vector_type(4)));
typedef bf16 bf16x8 __attribute__((ext_vector_type(8)));
typedef float f32x4 __attribute__((ext_vector_type(4)));
typedef float f32x16 __attribute__((ext_vector_type(16)));

#define T_DIM 365
#define SX    376      // LDS stride (bf16) for Xb
#define SH1   520
#define SH2   264
#define SCB   184      // combined: 128 seq + 32 stat
#define SC1   72
#define SC2   33

#define ROWS  64

// Union region: fp32 x staging (Phase A) aliased over sH1 / sCB / sC2.
#define SU_H1    0
#define SU_CB    66560
#define SU_C2    90112
#define SU_BYTES 98816

// ws element offsets (bf16 elements) — fragment-major packed layouts (UNCHANGED).
#define WT1_OFF  0
#define WT2_OFF  188416
#define WT3_OFF  319488
#define WTC1_OFF 352256
#define WTC2_OFF 362496
#define WTOTAL   364544

// sConst float offsets
#define OB1   0
#define OB2   512
#define OB3   768
#define OBC1  896
#define OBC2  960
#define OWS   992
#define OBS   1184
#define OWC3  1216
#define OBC3  1248
#define NCONST 1252

__global__ void prep_weights(const float* __restrict__ W1, const float* __restrict__ W2,
                             const float* __restrict__ W3, const float* __restrict__ Wc1,
                             const float* __restrict__ Wc2, bf16* __restrict__ ws) {
    int idx = blockIdx.x * 256 + threadIdx.x;
    if (idx >= WTOTAL) return;
    if (idx < WT2_OFF) {
        int t = idx;
        int j = t & 7, lane = (t >> 3) & 63, f = t >> 9;
        int ks = f % 23; f /= 23;
        int nt = f & 3, wv = f >> 2;
        int n = 128 * wv + 32 * nt + (lane & 31);
        int k = 16 * ks + (lane >> 5) * 8 + j;
        ws[idx] = (k < T_DIM) ? (bf16)W1[k * 512 + n] : (bf16)0.0f;
    } else if (idx < WT3_OFF) {
        int t = idx - WT2_OFF;
        int j = t & 7, lane = (t >> 3) & 63, f = t >> 9;
        int ks = f & 31; f >>= 5;
        int nt = f & 1, wv = f >> 1;
        int n = 64 * wv + 32 * nt + (lane & 31);
        int k = 16 * ks + (lane >> 5) * 8 + j;
        ws[idx] = (bf16)W2[k * 256 + n];
    } else if (idx < WTC1_OFF) {
        int t = idx - WT3_OFF;
        int j = t & 7, lane = (t >> 3) & 63, f = t >> 9;
        int ks = f & 15, wv = f >> 4;
        int n = 32 * wv + (lane & 31);
        int k = 16 * ks + (lane >> 5) * 8 + j;
        ws[idx] = (bf16)W3[k * 128 + n];
    } else if (idx < WTC2_OFF) {
        int t = idx - WTC1_OFF;
        int j = t & 7, lane = (t >> 3) & 63, f = t >> 9;
        int ks = f % 5; f /= 5;
        int nt = f & 1, g = f >> 1;
        int n = 16 * (2 * g + nt) + (lane & 15);
        int k = 32 * ks + (lane >> 4) * 8 + j;
        ws[idx] = (bf16)Wc1[k * 64 + n];
    } else {
        int t = idx - WTC2_OFF;
        int j = t & 7, lane = (t >> 3) & 63, f = t >> 9;
        int ks = f & 1, nt = f >> 1;
        int n = 16 * nt + (lane & 15);
        int k = 32 * ks + (lane >> 4) * 8 + j;
        ws[idx] = (bf16)Wc2[k * 32 + n];
    }
}

__device__ inline f32x16 z16() {
    f32x16 v;
#pragma unroll
    for (int i = 0; i < 16; ++i) v[i] = 0.0f;
    return v;
}
__device__ inline f32x4 z4() {
    f32x4 v;
#pragma unroll
    for (int i = 0; i < 4; ++i) v[i] = 0.0f;
    return v;
}

// LDS-visibility barrier (no vmcnt drain — keeps global prefetches in flight)
__device__ __forceinline__ void bar_lgkm() {
    asm volatile("s_waitcnt lgkmcnt(0)" ::: "memory");
    __builtin_amdgcn_s_barrier();
}
// Full barrier (after global_load_lds staging)
__device__ __forceinline__ void bar_all() {
    asm volatile("s_waitcnt vmcnt(0) lgkmcnt(0)" ::: "memory");
    __builtin_amdgcn_s_barrier();
}

__device__ __forceinline__ void stage16(const float* g, void* ldsbase) {
    __builtin_amdgcn_global_load_lds(
        (const __attribute__((address_space(1))) void*)g,
        (__attribute__((address_space(3))) void*)ldsbase, 16, 0, 0);
}

__global__ __launch_bounds__(512, 2) void fused_mlp(
    const float* __restrict__ x, const bf16* __restrict__ wt,
    const float* __restrict__ b1, const float* __restrict__ b2, const float* __restrict__ b3,
    const float* __restrict__ Ws, const float* __restrict__ bs,
    const float* __restrict__ bc1, const float* __restrict__ bc2,
    const float* __restrict__ Wc3, const float* __restrict__ bc3,
    float* __restrict__ out)
{
    __shared__ __align__(16) char  sU[SU_BYTES];   // staging | {sH1, sCB, sC2}
    __shared__ __align__(16) bf16  sXb[ROWS * SX]; // Xb bf16; reused as H2 [64][SH2]
    __shared__ __align__(16) float sConst[NCONST];

    bf16*  sH1 = (bf16*)(sU + SU_H1);
    bf16*  sCB = (bf16*)(sU + SU_CB);
    float* sC2 = (float*)(sU + SU_C2);
    float* stg = (float*)sU;

    const int tid  = threadIdx.x;
    const int lane = tid & 63;
    const int wv   = tid >> 6;        // 0..7
    const int row0 = blockIdx.x * ROWS;

    // ================= A1: issue x staging + L1 weight prefetch + consts ==========
    const float* xt = x + (size_t)row0 * T_DIM;   // 64*1460B region, 16B-aligned
    {
        // 92 dwordx4 wave-instructions total: slot s = i*8 + wv
#pragma unroll
        for (int i = 0; i < 12; ++i) {
            int s = i * 8 + wv;
            if (s < 91) {
                stage16(xt + s * 256 + lane * 4, (void*)(sU + (size_t)s * 1024));
            } else if (s == 91) {
                if (lane < 16)
                    stage16(xt + s * 256 + lane * 4, (void*)(sU + (size_t)s * 1024));
            }
        }
    }
    const bf16* bp1 = wt + WT1_OFF + (size_t)(2 * wv) * 11776 + (size_t)lane * 8;
    bf16x8 pf1[2][2];
#pragma unroll
    for (int d = 0; d < 2; ++d) {
        pf1[d][0] = *(const bf16x8*)(bp1 + d * 512);
        pf1[d][1] = *(const bf16x8*)(bp1 + 11776 + d * 512);
    }
    sConst[OB1 + tid] = b1[tid];
    if (tid < 256)      sConst[OB2 + tid]        = b2[tid];
    else if (tid < 384) sConst[OB3 + tid - 256]  = b3[tid - 256];
    else if (tid < 448) sConst[OBC1 + tid - 384] = bc1[tid - 384];
    else if (tid < 480) sConst[OBC2 + tid - 448] = bc2[tid - 448];
    else                sConst[OWS + tid - 480]  = Ws[tid - 480];
    if (tid < 160)      sConst[OWS + 32 + tid]   = Ws[32 + tid];
    else if (tid < 192) sConst[OBS + tid - 160]  = bs[tid - 160];
    else if (tid < 224) sConst[OWC3 + tid - 192] = Wc3[tid - 192];
    else if (tid == 224) sConst[OBC3]            = bc3[0];

    bar_all();   // staging + consts visible to all waves

    // ================= A2: stats + Xb bf16 from LDS staging =======================
    {
        const int r   = tid >> 3;          // row 0..63
        const int j   = tid & 7;           // 8 threads per row
        const int c0  = 46 * j;            // contiguous 46-col segment (43 for j==7)
        const int cnt = (j < 7) ? 46 : 43;
        const float* srow = stg + r * 365 + c0;
        bf16* xb = sXb + r * SX + c0;
        float s1 = 0.f, s2 = 0.f, s3 = 0.f, s4 = 0.f;
        float mn = 3.4e38f, mx = -3.4e38f;
#pragma unroll
        for (int i = 0; i < 46; ++i) {
            float v  = srow[i];            // in-bounds of sU even when i>=cnt
            bool ok  = (i < cnt);
            float vv = ok ? v : 0.0f;
            s1 += vv;
            float q = vv * vv;
            s2 += q; s3 += q * vv; s4 += q * q;
            mn = fminf(mn, ok ? v : 3.4e38f);
            mx = fmaxf(mx, ok ? v : -3.4e38f);
            xb[i] = (bf16)vv;
        }
#pragma unroll
        for (int m = 1; m < 8; m <<= 1) {
            s1 += __shfl_xor(s1, m); s2 += __shfl_xor(s2, m);
            s3 += __shfl_xor(s3, m); s4 += __shfl_xor(s4, m);
            mn = fminf(mn, __shfl_xor(mn, m));
            mx = fmaxf(mx, __shfl_xor(mx, m));
        }
        const float Tf = (float)T_DIM;
        float mu = s1 / Tf;
        float M2 = fmaxf(s2 - s1 * mu, 0.0f);
        float M3 = s3 - 3.f * mu * s2 + 2.f * Tf * mu * mu * mu;
        float M4 = s4 - 4.f * mu * s3 + 6.f * mu * mu * s2 - 3.f * Tf * mu * mu * mu * mu;
        float var = M2 / (Tf - 1.f);
        float sd  = sqrtf(var);
        float sk  = (M3 / Tf) / (sd * sd * sd + 1e-8f);
        float ku  = (M4 / Tf) / (var * var + 1e-8f);

        bar_lgkm();  // all staging reads done; Xb complete

        // A3: stat features -> sCB cols 128..159 (aliases staging region: safe now)
#pragma unroll
        for (int cc = 0; cc < 4; ++cc) {
            int n = 4 * j + cc;
            float v = sConst[OBS + n]
                    + mu * sConst[OWS + 0*32+n] + sd * sConst[OWS + 1*32+n]
                    + mn * sConst[OWS + 2*32+n] + mx * sConst[OWS + 3*32+n]
                    + sk * sConst[OWS + 4*32+n] + ku * sConst[OWS + 5*32+n];
            sCB[r * SCB + 128 + n] = (bf16)v;
        }
    }

    const int l31   = lane & 31;
    const int lhalf = lane >> 5;

    // ================= Layer 1: [64,368] x [368,512] -> H1 ========================
    // depth-2 register pipeline on BOTH operands: fa(k+1) read during MFMAs of k.
    const bf16* bp2 = wt + WT2_OFF + (size_t)wv * 16384 + (size_t)lane * 8;
    bf16x8 pf2[4];
    {
        f32x16 a00 = z16(), a01 = z16(), a10 = z16(), a11 = z16();
        const bf16* ap0 = sXb + l31 * SX + lhalf * 8;
        const bf16* ap1 = sXb + (32 + l31) * SX + lhalf * 8;
        bf16x8 fc0 = *(const bf16x8*)(ap0);
        bf16x8 fc1 = *(const bf16x8*)(ap1);
#pragma unroll
        for (int ks = 0; ks < 23; ++ks) {
            bf16x8 fn0 = fc0, fn1 = fc1;
            if (ks + 1 < 23) {
                fn0 = *(const bf16x8*)(ap0 + 16 * (ks + 1));
                fn1 = *(const bf16x8*)(ap1 + 16 * (ks + 1));
            }
            bf16x8 w0 = pf1[ks & 1][0];
            bf16x8 w1 = pf1[ks & 1][1];
            if (ks + 2 < 23) {
                pf1[ks & 1][0] = *(const bf16x8*)(bp1 + (ks + 2) * 512);
                pf1[ks & 1][1] = *(const bf16x8*)(bp1 + 11776 + (ks + 2) * 512);
            }
            a00 = __builtin_amdgcn_mfma_f32_32x32x16_bf16(fc0, w0, a00, 0, 0, 0);
            a01 = __builtin_amdgcn_mfma_f32_32x32x16_bf16(fc0, w1, a01, 0, 0, 0);
            a10 = __builtin_amdgcn_mfma_f32_32x32x16_bf16(fc1, w0, a10, 0, 0, 0);
            a11 = __builtin_amdgcn_mfma_f32_32x32x16_bf16(fc1, w1, a11, 0, 0, 0);
            fc0 = fn0; fc1 = fn1;
        }
#pragma unroll
        for (int d = 0; d < 4; ++d)
            pf2[d] = *(const bf16x8*)(bp2 + d * 512);
#pragma unroll
        for (int nt = 0; nt < 2; ++nt) {
            int col = 64 * wv + 32 * nt + l31;
            float bias = sConst[OB1 + col];
            const f32x16& am0 = nt ? a01 : a00;
            const f32x16& am1 = nt ? a11 : a10;
#pragma unroll
            for (int g = 0; g < 4; ++g) {
#pragma unroll
                for (int rr = 0; rr < 4; ++rr) {
                    int rowi = rr + 8 * g + 4 * lhalf;
                    sH1[rowi * SH1 + col]        = (bf16)fmaxf(am0[4 * g + rr] + bias, 0.0f);
                    sH1[(32 + rowi) * SH1 + col] = (bf16)fmaxf(am1[4 * g + rr] + bias, 0.0f);
                }
            }
        }
    }
    bar_lgkm();

    // ================= Layer 2: [64,512] x [512,256] -> H2 (in sXb) ===============
    const bf16* bp3 = wt + WT3_OFF + (size_t)(wv & 3) * 8192 + (size_t)lane * 8;
    bf16x8 pf3[4];
    {
        f32x16 ac0 = z16(), ac1 = z16();
        const bf16* ap0 = sH1 + l31 * SH1 + lhalf * 8;
        const bf16* ap1 = sH1 + (32 + l31) * SH1 + lhalf * 8;
        bf16x8 fc0 = *(const bf16x8*)(ap0);
        bf16x8 fc1 = *(const bf16x8*)(ap1);
#pragma unroll
        for (int ks = 0; ks < 32; ++ks) {
            bf16x8 fn0 = fc0, fn1 = fc1;
            if (ks + 1 < 32) {
                fn0 = *(const bf16x8*)(ap0 + 16 * (ks + 1));
                fn1 = *(const bf16x8*)(ap1 + 16 * (ks + 1));
            }
            bf16x8 w = pf2[ks & 3];
            if (ks + 4 < 32)
                pf2[ks & 3] = *(const bf16x8*)(bp2 + (ks + 4) * 512);
            ac0 = __builtin_amdgcn_mfma_f32_32x32x16_bf16(fc0, w, ac0, 0, 0, 0);
            ac1 = __builtin_amdgcn_mfma_f32_32x32x16_bf16(fc1, w, ac1, 0, 0, 0);
            fc0 = fn0; fc1 = fn1;
        }
#pragma unroll
        for (int d = 0; d < 4; ++d)
            pf3[d] = *(const bf16x8*)(bp3 + d * 512);
        bf16* H2 = sXb;
        int col = 32 * wv + l31;
        float bias = sConst[OB2 + col];
#pragma unroll
        for (int g = 0; g < 4; ++g) {
#pragma unroll
            for (int rr = 0; rr < 4; ++rr) {
                int rowi = rr + 8 * g + 4 * lhalf;
                H2[rowi * SH2 + col]        = (bf16)fmaxf(ac0[4 * g + rr] + bias, 0.0f);
                H2[(32 + rowi) * SH2 + col] = (bf16)fmaxf(ac1[4 * g + rr] + bias, 0.0f);
            }
        }
    }
    bar_lgkm();

    // ================= Layer 3: [64,256] x [256,128] -> seq (sCB 0..127) ==========
    const bf16* bpc1 = wt + WTC1_OFF + (size_t)(wv >> 2) * 5120 + (size_t)lane * 8;
    bf16x8 w0c[5], w1c[5];
    {
        const int ct = wv & 3;
        const int m3 = wv >> 2;
        f32x16 acc = z16();
        const bf16* H2 = sXb;
        const bf16* ap = H2 + (32 * m3 + l31) * SH2 + lhalf * 8;
        bf16x8 fc = *(const bf16x8*)(ap);
#pragma unroll
        for (int ks = 0; ks < 16; ++ks) {
            bf16x8 fn = fc;
            if (ks + 1 < 16)
                fn = *(const bf16x8*)(ap + 16 * (ks + 1));
            bf16x8 w = pf3[ks & 3];
            if (ks + 4 < 16)
                pf3[ks & 3] = *(const bf16x8*)(bp3 + (ks + 4) * 512);
            acc = __builtin_amdgcn_mfma_f32_32x32x16_bf16(fc, w, acc, 0, 0, 0);
            fc = fn;
        }
#pragma unroll
        for (int ks = 0; ks < 5; ++ks) {
            w0c[ks] = *(const bf16x8*)(bpc1 + ks * 512);
            w1c[ks] = *(const bf16x8*)(bpc1 + 2560 + ks * 512);
        }
        int col = 32 * ct + l31;
        float bias = sConst[OB3 + col];
#pragma unroll
        for (int g = 0; g < 4; ++g) {
#pragma unroll
            for (int rr = 0; rr < 4; ++rr) {
                int rowi = 32 * m3 + rr + 8 * g + 4 * lhalf;
                sCB[rowi * SCB + col] = (bf16)fmaxf(acc[4 * g + rr] + bias, 0.0f);
            }
        }
    }
    bar_lgkm();

    // ================= c1: [64,160] x [160,64] -> C1 (16x16x32) ===================
    const bf16* bpc2 = wt + WTC2_OFF + (size_t)(wv >> 2) * 1024 + (size_t)lane * 8;
    bf16x8 wc2[2];
    {
        const int l15 = lane & 15;
        const int lq  = lane >> 4;
        const int mt  = wv & 3;
        const int g2  = wv >> 2;
        f32x4 ac0 = z4(), ac1 = z4();
        const bf16* ap = sCB + (16 * mt + l15) * SCB + lq * 8;
        bf16x8 av[5];
#pragma unroll
        for (int ks = 0; ks < 5; ++ks)
            av[ks] = *(const bf16x8*)(ap + 32 * ks);
#pragma unroll
        for (int ks = 0; ks < 5; ++ks) {
            ac0 = __builtin_amdgcn_mfma_f32_16x16x32_bf16(av[ks], w0c[ks], ac0, 0, 0, 0);
            ac1 = __builtin_amdgcn_mfma_f32_16x16x32_bf16(av[ks], w1c[ks], ac1, 0, 0, 0);
        }
#pragma unroll
        for (int ks = 0; ks < 2; ++ks)
            wc2[ks] = *(const bf16x8*)(bpc2 + ks * 512);
        bf16* C1 = sH1;
#pragma unroll
        for (int nt = 0; nt < 2; ++nt) {
            int col = 16 * (2 * g2 + nt) + l15;
            float bias = sConst[OBC1 + col];
            const f32x4& ac = nt ? ac1 : ac0;
#pragma unroll
            for (int reg = 0; reg < 4; ++reg) {
                int m = 16 * mt + lq * 4 + reg;
                C1[m * SC1 + col] = (bf16)fmaxf(ac[reg] + bias, 0.0f);
            }
        }
    }
    bar_lgkm();

    // ================= c2: [64,64] x [64,32] -> sC2 (f32) =========================
    {
        const int l15 = lane & 15;
        const int lq  = lane >> 4;
        const int mt  = wv & 3;
        const int nt2 = wv >> 2;
        f32x4 acc = z4();
        const bf16* C1 = sH1;
        const bf16* ap = C1 + (16 * mt + l15) * SC1 + lq * 8;
        bf16x8 av[2];
#pragma unroll
        for (int ks = 0; ks < 2; ++ks)
            av[ks] = *(const bf16x8*)(ap + 32 * ks);
#pragma unroll
        for (int ks = 0; ks < 2; ++ks)
            acc = __builtin_amdgcn_mfma_f32_16x16x32_bf16(av[ks], wc2[ks], acc, 0, 0, 0);
        int col = 16 * nt2 + l15;
        float bias = sConst[OBC2 + col];
#pragma unroll
        for (int reg = 0; reg < 4; ++reg) {
            int m = 16 * mt + lq * 4 + reg;
            sC2[m * SC2 + col] = fmaxf(acc[reg] + bias, 0.0f);
        }
    }
    bar_lgkm();

    // ================= final: 32 -> 1 dot, sigmoid*4+6 ============================
    if (tid < ROWS) {
        const float* c2r = sC2 + tid * SC2;
        float z = sConst[OBC3];
#pragma unroll
        for (int k = 0; k < 32; ++k) z += c2r[k] * sConst[OWC3 + k];
        float sg = 1.0f / (1.0f + __expf(-z));
        out[row0 + tid] = sg * 4.0f + 6.0f;
    }
}

extern "C" void kernel_launch(void* const* d_in, const int* in_sizes, int n_in,
                              void* d_out, int out_size, void* d_ws, size_t ws_size,
                              hipStream_t stream) {
    const float* x   = (const float*)d_in[0];
    const float* W1  = (const float*)d_in[1];
    const float* b1  = (const float*)d_in[2];
    const float* W2  = (const float*)d_in[3];
    const float* b2  = (const float*)d_in[4];
    const float* W3  = (const float*)d_in[5];
    const float* b3  = (const float*)d_in[6];
    const float* Ws  = (const float*)d_in[7];
    const float* bs  = (const float*)d_in[8];
    const float* Wc1 = (const float*)d_in[9];
    const float* bc1 = (const float*)d_in[10];
    const float* Wc2 = (const float*)d_in[11];
    const float* bc2 = (const float*)d_in[12];
    const float* Wc3 = (const float*)d_in[13];
    const float* bc3 = (const float*)d_in[14];
    float* out = (float*)d_out;
    bf16* wt = (bf16*)d_ws;

    const int B = in_sizes[0] / T_DIM;          // 65536
    prep_weights<<<(WTOTAL + 255) / 256, 256, 0, stream>>>(W1, W2, W3, Wc1, Wc2, wt);
    fused_mlp<<<B / ROWS, 512, 0, stream>>>(x, wt, b1, b2, b3, Ws, bs, bc1, bc2, Wc3, bc3, out);
}